// Round 1
// baseline (612.538 us; speedup 1.0000x reference)
//
#include <hip/hip_runtime.h>
#include <hip/hip_bf16.h>

#define NN 50000
#define NE 800000
#define HID 128
#define NB 32
#define EIN 288   // 2*HID + NB

typedef short short8 __attribute__((ext_vector_type(8)));
typedef float f32x4 __attribute__((ext_vector_type(4)));

static __device__ __forceinline__ short f2bf(float x) {
    // round-to-nearest-even fp32 -> bf16
    unsigned int u = __float_as_uint(x);
    unsigned int r = (u + 0x7fffu + ((u >> 16) & 1u)) >> 16;
    return (short)r;
}
static __device__ __forceinline__ float bf2f(unsigned short s) {
    return __uint_as_float(((unsigned int)s) << 16);
}

// ---- prep: node features fp32 -> bf16 ----
__global__ void prep_nf(const float* __restrict__ nf, short* __restrict__ nfb) {
    int i = blockIdx.x * 256 + threadIdx.x;          // 800000 threads, 8 elems each
    const float4* sp = (const float4*)nf + (size_t)i * 2;
    float4 a = sp[0], b = sp[1];
    short8 o;
    o[0] = f2bf(a.x); o[1] = f2bf(a.y); o[2] = f2bf(a.z); o[3] = f2bf(a.w);
    o[4] = f2bf(b.x); o[5] = f2bf(b.y); o[6] = f2bf(b.z); o[7] = f2bf(b.w);
    *((short8*)nfb + i) = o;
}

// ---- prep: W1 [288,128] -> W1t [128,288] bf16 ; W2 [128,128] -> W2t [128,128] bf16 ----
__global__ void prep_w(const float* __restrict__ W1, const float* __restrict__ W2,
                       short* __restrict__ W1t, short* __restrict__ W2t) {
    int t = blockIdx.x * 256 + threadIdx.x;
    if (t < EIN * HID) {                 // 36864
        int n = t / EIN, k = t % EIN;
        W1t[t] = f2bf(W1[k * HID + n]);
    } else {
        int t2 = t - EIN * HID;
        if (t2 < HID * HID) {            // 16384
            int n = t2 / HID, k = t2 % HID;
            W2t[t2] = f2bf(W2[k * HID + n]);
        }
    }
}

// ---- fused edge MLP + scatter ----
// 64 edges per block, 256 threads (4 waves). Each wave owns a 32-col slice.
__launch_bounds__(256, 2)
__global__ void edge_kernel(const short* __restrict__ nfb,
                            const float* __restrict__ pos,
                            const int* __restrict__ srcI,
                            const int* __restrict__ dstI,
                            const short* __restrict__ W1t,
                            const float* __restrict__ b1,
                            const short* __restrict__ W2t,
                            const float* __restrict__ b2,
                            float* __restrict__ upd,      // [NN,HID] accumulator (d_out)
                            float* __restrict__ degree) { // [NN]
    __shared__ short As[64 * 296];   // padded 288->296 (2-way banks, free)
    __shared__ short Ps[64 * 136];   // padded 128->136
    __shared__ float d_sh[64];
    __shared__ int   dn_sh[64];

    const int tid  = threadIdx.x;
    const int wave = tid >> 6;
    const int lane = tid & 63;
    const int quad = lane >> 4;
    const int l15  = lane & 15;
    const int e0   = blockIdx.x * 64;

    // ---- stage: gather node rows (bf16) + positions/degree ----
    {
        int es = tid >> 2;     // 0..63 edge within tile
        int pt = tid & 3;      // 0..3, 32 cols each
        int e = e0 + es;
        int s = srcI[e];
        int d = dstI[e];
        const int4* sp = (const int4*)(nfb + (size_t)s * HID + pt * 32);
        const int4* dp = (const int4*)(nfb + (size_t)d * HID + pt * 32);
        int4* as = (int4*)(As + es * 296 + pt * 32);
        int4* ad = (int4*)(As + es * 296 + 128 + pt * 32);
        #pragma unroll
        for (int j = 0; j < 4; ++j) as[j] = sp[j];
        #pragma unroll
        for (int j = 0; j < 4; ++j) ad[j] = dp[j];
        if (pt == 0) {
            dn_sh[es] = d;
            float dx = pos[d * 3 + 0] - pos[s * 3 + 0];
            float dy = pos[d * 3 + 1] - pos[s * 3 + 1];
            float dz = pos[d * 3 + 2] - pos[s * 3 + 2];
            float dist = sqrtf(dx * dx + dy * dy + dz * dz);
            d_sh[es] = fminf(dist, 5.0f);
            atomicAdd(degree + d, 1.0f);
        }
    }
    __syncthreads();

    // ---- RBF into cols [256,288) ----
    {
        int es = tid >> 2;
        int pt = tid & 3;
        float dd = d_sh[es];
        const float step  = 5.0f / 31.0f;
        const float width = 0.5f * (step + 0.01f);
        const float coef  = -0.5f / (width * width);
        short8 r;
        #pragma unroll
        for (int j = 0; j < 8; ++j) {
            float c = step * (float)(pt * 8 + j);
            float t = dd - c;
            r[j] = f2bf(__expf(coef * t * t));
        }
        *(short8*)(As + es * 296 + 256 + pt * 8) = r;
    }
    __syncthreads();

    // ---- layer 1: [64x288] @ [288x128], wave covers cols [wave*32, wave*32+32) ----
    f32x4 acc[4][2];
    #pragma unroll
    for (int mt = 0; mt < 4; ++mt)
        #pragma unroll
        for (int nt = 0; nt < 2; ++nt) acc[mt][nt] = (f32x4){0.f, 0.f, 0.f, 0.f};

    #pragma unroll
    for (int kk = 0; kk < 9; ++kk) {
        int ko = kk * 32 + quad * 8;
        short8 a[4];
        #pragma unroll
        for (int mt = 0; mt < 4; ++mt)
            a[mt] = *(const short8*)(As + (mt * 16 + l15) * 296 + ko);
        #pragma unroll
        for (int nt = 0; nt < 2; ++nt) {
            int n = wave * 32 + nt * 16 + l15;
            short8 b = *(const short8*)(W1t + n * EIN + ko);
            #pragma unroll
            for (int mt = 0; mt < 4; ++mt)
                acc[mt][nt] = __builtin_amdgcn_mfma_f32_16x16x32_bf16(a[mt], b, acc[mt][nt], 0, 0, 0);
        }
    }

    // ---- bias + SiLU, write P to LDS in row-major for layer-2 A-frags ----
    #pragma unroll
    for (int nt = 0; nt < 2; ++nt) {
        int col = wave * 32 + nt * 16 + l15;
        float bias = b1[col];
        #pragma unroll
        for (int mt = 0; mt < 4; ++mt) {
            #pragma unroll
            for (int r = 0; r < 4; ++r) {
                int row = mt * 16 + quad * 4 + r;
                float x = acc[mt][nt][r] + bias;
                float p = x / (1.0f + __expf(-x));
                Ps[row * 136 + col] = f2bf(p);
            }
        }
    }
    __syncthreads();

    // ---- layer 2: [64x128] @ [128x128] ----
    f32x4 acc2[4][2];
    #pragma unroll
    for (int mt = 0; mt < 4; ++mt)
        #pragma unroll
        for (int nt = 0; nt < 2; ++nt) acc2[mt][nt] = (f32x4){0.f, 0.f, 0.f, 0.f};

    #pragma unroll
    for (int kk = 0; kk < 4; ++kk) {
        int ko = kk * 32 + quad * 8;
        short8 a[4];
        #pragma unroll
        for (int mt = 0; mt < 4; ++mt)
            a[mt] = *(const short8*)(Ps + (mt * 16 + l15) * 136 + ko);
        #pragma unroll
        for (int nt = 0; nt < 2; ++nt) {
            int n = wave * 32 + nt * 16 + l15;
            short8 b = *(const short8*)(W2t + n * HID + ko);
            #pragma unroll
            for (int mt = 0; mt < 4; ++mt)
                acc2[mt][nt] = __builtin_amdgcn_mfma_f32_16x16x32_bf16(a[mt], b, acc2[mt][nt], 0, 0, 0);
        }
    }

    // ---- bias + scatter-add to destination nodes ----
    #pragma unroll
    for (int nt = 0; nt < 2; ++nt) {
        int col = wave * 32 + nt * 16 + l15;
        float bias = b2[col];
        #pragma unroll
        for (int mt = 0; mt < 4; ++mt) {
            #pragma unroll
            for (int r = 0; r < 4; ++r) {
                int row = mt * 16 + quad * 4 + r;
                int node = dn_sh[row];
                atomicAdd(upd + (size_t)node * HID + col, acc2[mt][nt][r] + bias);
            }
        }
    }
}

// ---- normalize by degree + @Wo + bo, in place on d_out ----
// 32 nodes per block; Wo staged in LDS as bf16 (accuracy kept by fp32 u + fp32 accum).
__launch_bounds__(256, 2)
__global__ void out_kernel(float* __restrict__ out,
                           const float* __restrict__ degree,
                           const float* __restrict__ Wo,
                           const float* __restrict__ bo) {
    __shared__ unsigned short Wo_s[HID * HID];   // 32 KB
    __shared__ float u_sh[2 * HID];

    int tid = threadIdx.x;
    #pragma unroll
    for (int i = 0; i < 16; ++i) {
        int idx4 = tid + i * 256;                 // 4096 float4 total
        float4 w = ((const float4*)Wo)[idx4];
        unsigned short* p = Wo_s + idx4 * 4;
        p[0] = (unsigned short)f2bf(w.x);
        p[1] = (unsigned short)f2bf(w.y);
        p[2] = (unsigned short)f2bf(w.z);
        p[3] = (unsigned short)f2bf(w.w);
    }
    int col  = tid & 127;
    int pair = tid >> 7;
    float bias = bo[col];
    int n0 = blockIdx.x * 32;
    __syncthreads();

    for (int it = 0; it < 16; ++it) {
        int node = n0 + it * 2 + pair;
        float v = 0.0f;
        if (node < NN) {
            float inv = 1.0f / fmaxf(degree[node], 1.0f);
            v = out[(size_t)node * HID + col] * inv;
        }
        u_sh[pair * HID + col] = v;
        __syncthreads();
        float acc = bias;
        for (int k = 0; k < HID; ++k)
            acc = fmaf(u_sh[pair * HID + k], bf2f(Wo_s[k * HID + col]), acc);
        if (node < NN)
            out[(size_t)node * HID + col] = acc;
        __syncthreads();
    }
}

extern "C" void kernel_launch(void* const* d_in, const int* in_sizes, int n_in,
                              void* d_out, int out_size, void* d_ws, size_t ws_size,
                              hipStream_t stream) {
    const float* nf  = (const float*)d_in[0];
    const float* pos = (const float*)d_in[1];
    const int*   ei  = (const int*)d_in[2];
    const float* W1  = (const float*)d_in[3];
    const float* b1  = (const float*)d_in[4];
    const float* W2  = (const float*)d_in[5];
    const float* b2  = (const float*)d_in[6];
    const float* Wo  = (const float*)d_in[7];
    const float* bo  = (const float*)d_in[8];
    float* out = (float*)d_out;

    char* ws = (char*)d_ws;
    short* nfb    = (short*)ws;                                   // 12,800,000 B
    short* W1t    = (short*)(ws + 12800000);                      //     73,728 B
    short* W2t    = (short*)(ws + 12800000 + 73728);              //     32,768 B
    float* degree = (float*)(ws + 12800000 + 73728 + 32768);      //    200,000 B

    hipMemsetAsync(out, 0, (size_t)NN * HID * sizeof(float), stream);
    hipMemsetAsync(degree, 0, (size_t)NN * sizeof(float), stream);

    prep_nf<<<3125, 256, 0, stream>>>(nf, nfb);
    prep_w<<<208, 256, 0, stream>>>(W1, W2, W1t, W2t);
    edge_kernel<<<NE / 64, 256, 0, stream>>>(nfb, pos, ei, ei + NE,
                                             W1t, b1, W2t, b2, out, degree);
    out_kernel<<<(NN + 31) / 32, 256, 0, stream>>>(out, degree, Wo, bo);
}

// Round 2
// 524.369 us; speedup vs baseline: 1.1681x; 1.1681x over previous
//
#include <hip/hip_runtime.h>
#include <hip/hip_bf16.h>

#define NN 50000
#define NE 800000
#define HID 128
#define NB 32
#define EIN 288   // 2*HID + NB
#define SCAN_B 196  // 196*256 = 50176 >= NN

typedef short short8 __attribute__((ext_vector_type(8)));
typedef float f32x4 __attribute__((ext_vector_type(4)));

static __device__ __forceinline__ short f2bf(float x) {
    unsigned int u = __float_as_uint(x);
    unsigned int r = (u + 0x7fffu + ((u >> 16) & 1u)) >> 16;
    return (short)r;
}

// ---- prep: node features fp32 -> bf16 ----
__global__ void prep_nf(const float* __restrict__ nf, short* __restrict__ nfb) {
    int i = blockIdx.x * 256 + threadIdx.x;
    const float4* sp = (const float4*)nf + (size_t)i * 2;
    float4 a = sp[0], b = sp[1];
    short8 o;
    o[0] = f2bf(a.x); o[1] = f2bf(a.y); o[2] = f2bf(a.z); o[3] = f2bf(a.w);
    o[4] = f2bf(b.x); o[5] = f2bf(b.y); o[6] = f2bf(b.z); o[7] = f2bf(b.w);
    *((short8*)nfb + i) = o;
}

// ---- prep: transpose W1/W2/Wo to N-major bf16 ----
__global__ void prep_w(const float* __restrict__ W1, const float* __restrict__ W2,
                       const float* __restrict__ Wo,
                       short* __restrict__ W1t, short* __restrict__ W2t,
                       short* __restrict__ Wot) {
    int t = blockIdx.x * 256 + threadIdx.x;
    if (t < EIN * HID) {                         // 36864
        int n = t / EIN, k = t % EIN;
        W1t[t] = f2bf(W1[k * HID + n]);
    } else if ((t -= EIN * HID) < HID * HID) {   // 16384
        int n = t / HID, k = t % HID;
        W2t[t] = f2bf(W2[k * HID + n]);
    } else if ((t -= HID * HID) < HID * HID) {   // 16384
        int n = t / HID, k = t % HID;
        Wot[t] = f2bf(Wo[k * HID + n]);
    }
}

// ---- counting sort by dst: histogram, 2-level exclusive scan, permute ----
__global__ void k_hist(const int* __restrict__ dst, int* __restrict__ counts) {
    int e = blockIdx.x * 256 + threadIdx.x;
    atomicAdd(&counts[dst[e]], 1);
}

__global__ void k_scan1(const int* __restrict__ counts, int* __restrict__ scanEx,
                        int* __restrict__ blockSum) {
    __shared__ int s[256];
    int t = threadIdx.x, idx = blockIdx.x * 256 + t;
    int v = (idx < NN) ? counts[idx] : 0;
    s[t] = v; __syncthreads();
    #pragma unroll
    for (int off = 1; off < 256; off <<= 1) {
        int x = (t >= off) ? s[t - off] : 0;
        __syncthreads();
        s[t] += x;
        __syncthreads();
    }
    scanEx[idx] = s[t] - v;
    if (t == 255) blockSum[blockIdx.x] = s[255];
}

__global__ void k_scan2(const int* __restrict__ blockSum, int* __restrict__ blockBase) {
    __shared__ int s[256];
    int t = threadIdx.x;
    int v = (t < SCAN_B) ? blockSum[t] : 0;
    s[t] = v; __syncthreads();
    #pragma unroll
    for (int off = 1; off < 256; off <<= 1) {
        int x = (t >= off) ? s[t - off] : 0;
        __syncthreads();
        s[t] += x;
        __syncthreads();
    }
    blockBase[t] = s[t] - v;
}

__global__ void k_scan3(const int* __restrict__ scanEx, const int* __restrict__ blockBase,
                        int* __restrict__ nodeBase, int* __restrict__ cursor) {
    int t = threadIdx.x, b = blockIdx.x, idx = b * 256 + t;
    if (idx < NN) {
        nodeBase[idx] = scanEx[idx] + blockBase[b];
        cursor[idx] = 0;
    }
}

__global__ void k_permute(const int* __restrict__ src, const int* __restrict__ dst,
                          const int* __restrict__ nodeBase, int* __restrict__ cursor,
                          int* __restrict__ srcS, int* __restrict__ dstS) {
    int e = blockIdx.x * 256 + threadIdx.x;
    int d = dst[e];
    int r = nodeBase[d] + atomicAdd(&cursor[d], 1);
    srcS[r] = src[e];
    dstS[r] = d;
}

// ---- fused edge MLP + run-merged scatter (edges sorted by dst) ----
// 64 edges/block, 4 waves, each wave a 32-col slice. LDS: As/Ps share one union
// buffer (38.4 KB -> 4 blocks/CU).
__launch_bounds__(256, 4)
__global__ void edge_kernel(const short* __restrict__ nfb,
                            const float* __restrict__ pos,
                            const int* __restrict__ srcS,
                            const int* __restrict__ dstS,
                            const short* __restrict__ W1t,
                            const float* __restrict__ b1,
                            const short* __restrict__ W2t,
                            const float* __restrict__ b2,
                            float* __restrict__ upd) {
    __shared__ short U[64 * 296];   // phase A: As [64,296]; phase B: Ps [64,136]
    __shared__ int   dn_sh[64];

    const int tid  = threadIdx.x;
    const int wave = tid >> 6;
    const int lane = tid & 63;
    const int quad = lane >> 4;
    const int l15  = lane & 15;
    const int e0   = blockIdx.x * 64;

    // ---- stage: gather node rows + RBF (each thread computes its own dist) ----
    {
        int es = tid >> 2;     // edge within tile
        int pt = tid & 3;      // 32-col slice
        int e = e0 + es;
        int s = srcS[e];
        int d = dstS[e];
        const int4* sp = (const int4*)(nfb + (size_t)s * HID + pt * 32);
        const int4* dp = (const int4*)(nfb + (size_t)d * HID + pt * 32);
        int4* as = (int4*)(U + es * 296 + pt * 32);
        int4* ad = (int4*)(U + es * 296 + 128 + pt * 32);
        #pragma unroll
        for (int j = 0; j < 4; ++j) as[j] = sp[j];
        #pragma unroll
        for (int j = 0; j < 4; ++j) ad[j] = dp[j];
        if (pt == 0) dn_sh[es] = d;
        float dx = pos[d * 3 + 0] - pos[s * 3 + 0];
        float dy = pos[d * 3 + 1] - pos[s * 3 + 1];
        float dz = pos[d * 3 + 2] - pos[s * 3 + 2];
        float dd = fminf(sqrtf(dx * dx + dy * dy + dz * dz), 5.0f);
        const float step  = 5.0f / 31.0f;
        const float width = 0.5f * (step + 0.01f);
        const float coef  = -0.5f / (width * width);
        short8 r;
        #pragma unroll
        for (int j = 0; j < 8; ++j) {
            float c = step * (float)(pt * 8 + j);
            float t = dd - c;
            r[j] = f2bf(__expf(coef * t * t));
        }
        *(short8*)(U + es * 296 + 256 + pt * 8) = r;
    }
    __syncthreads();

    // ---- layer 1: [64x288] @ [288x128] ----
    f32x4 acc[4][2];
    #pragma unroll
    for (int mt = 0; mt < 4; ++mt)
        #pragma unroll
        for (int nt = 0; nt < 2; ++nt) acc[mt][nt] = (f32x4){0.f, 0.f, 0.f, 0.f};

    #pragma unroll
    for (int kk = 0; kk < 9; ++kk) {
        int ko = kk * 32 + quad * 8;
        short8 a[4];
        #pragma unroll
        for (int mt = 0; mt < 4; ++mt)
            a[mt] = *(const short8*)(U + (mt * 16 + l15) * 296 + ko);
        #pragma unroll
        for (int nt = 0; nt < 2; ++nt) {
            int n = wave * 32 + nt * 16 + l15;
            short8 b = *(const short8*)(W1t + n * EIN + ko);
            #pragma unroll
            for (int mt = 0; mt < 4; ++mt)
                acc[mt][nt] = __builtin_amdgcn_mfma_f32_16x16x32_bf16(a[mt], b, acc[mt][nt], 0, 0, 0);
        }
    }
    __syncthreads();   // all waves done reading As before Ps overwrites it

    // ---- bias + SiLU -> Ps (row-major, stride 136) ----
    #pragma unroll
    for (int nt = 0; nt < 2; ++nt) {
        int col = wave * 32 + nt * 16 + l15;
        float bias = b1[col];
        #pragma unroll
        for (int mt = 0; mt < 4; ++mt) {
            #pragma unroll
            for (int r = 0; r < 4; ++r) {
                int row = mt * 16 + quad * 4 + r;
                float x = acc[mt][nt][r] + bias;
                float p = x / (1.0f + __expf(-x));
                U[row * 136 + col] = f2bf(p);
            }
        }
    }
    __syncthreads();

    // ---- layer 2: [64x128] @ [128x128] ----
    f32x4 acc2[4][2];
    #pragma unroll
    for (int mt = 0; mt < 4; ++mt)
        #pragma unroll
        for (int nt = 0; nt < 2; ++nt) acc2[mt][nt] = (f32x4){0.f, 0.f, 0.f, 0.f};

    #pragma unroll
    for (int kk = 0; kk < 4; ++kk) {
        int ko = kk * 32 + quad * 8;
        short8 a[4];
        #pragma unroll
        for (int mt = 0; mt < 4; ++mt)
            a[mt] = *(const short8*)(U + (mt * 16 + l15) * 136 + ko);
        #pragma unroll
        for (int nt = 0; nt < 2; ++nt) {
            int n = wave * 32 + nt * 16 + l15;
            short8 b = *(const short8*)(W2t + n * HID + ko);
            #pragma unroll
            for (int mt = 0; mt < 4; ++mt)
                acc2[mt][nt] = __builtin_amdgcn_mfma_f32_16x16x32_bf16(a[mt], b, acc2[mt][nt], 0, 0, 0);
        }
    }

    // ---- bias + scatter with run-merging (dst sorted -> 4-row groups mostly one node) ----
    #pragma unroll
    for (int nt = 0; nt < 2; ++nt) {
        int col = wave * 32 + nt * 16 + l15;
        float bias = b2[col];
        #pragma unroll
        for (int mt = 0; mt < 4; ++mt) {
            int rbase = mt * 16 + quad * 4;
            int rnode = dn_sh[rbase];
            float run = 0.0f;
            #pragma unroll
            for (int r = 0; r < 4; ++r) {
                int node = dn_sh[rbase + r];
                float v = acc2[mt][nt][r] + bias;
                if (node != rnode) {
                    atomicAdd(upd + (size_t)rnode * HID + col, run);
                    rnode = node;
                    run = v;
                } else {
                    run += v;
                }
            }
            atomicAdd(upd + (size_t)rnode * HID + col, run);
        }
    }
}

// ---- normalize by degree + @Wo + bo (MFMA), in place on d_out ----
__launch_bounds__(256, 4)
__global__ void out_kernel(float* __restrict__ out,
                           const int* __restrict__ counts,
                           const short* __restrict__ Wot,
                           const float* __restrict__ bo) {
    __shared__ short A2[64 * 136];

    const int tid  = threadIdx.x;
    const int wave = tid >> 6;
    const int lane = tid & 63;
    const int quad = lane >> 4;
    const int l15  = lane & 15;
    const int n0   = blockIdx.x * 64;

    // stage: normalize + cvt bf16 into A-layout LDS
    {
        int row = tid >> 2, pt = tid & 3;
        int node = n0 + row;
        if (node < NN) {
            float inv = 1.0f / fmaxf((float)counts[node], 1.0f);
            const float4* p = (const float4*)(out + (size_t)node * HID + pt * 32);
            #pragma unroll
            for (int j = 0; j < 4; ++j) {
                float4 w0 = p[j * 2], w1 = p[j * 2 + 1];
                short8 o;
                o[0] = f2bf(w0.x * inv); o[1] = f2bf(w0.y * inv);
                o[2] = f2bf(w0.z * inv); o[3] = f2bf(w0.w * inv);
                o[4] = f2bf(w1.x * inv); o[5] = f2bf(w1.y * inv);
                o[6] = f2bf(w1.z * inv); o[7] = f2bf(w1.w * inv);
                *(short8*)(A2 + row * 136 + pt * 32 + j * 8) = o;
            }
        } else {
            short8 z = (short8){0, 0, 0, 0, 0, 0, 0, 0};
            #pragma unroll
            for (int j = 0; j < 4; ++j)
                *(short8*)(A2 + row * 136 + pt * 32 + j * 8) = z;
        }
    }
    __syncthreads();

    f32x4 acc[4][2];
    #pragma unroll
    for (int mt = 0; mt < 4; ++mt)
        #pragma unroll
        for (int nt = 0; nt < 2; ++nt) acc[mt][nt] = (f32x4){0.f, 0.f, 0.f, 0.f};

    #pragma unroll
    for (int kk = 0; kk < 4; ++kk) {
        int ko = kk * 32 + quad * 8;
        short8 a[4];
        #pragma unroll
        for (int mt = 0; mt < 4; ++mt)
            a[mt] = *(const short8*)(A2 + (mt * 16 + l15) * 136 + ko);
        #pragma unroll
        for (int nt = 0; nt < 2; ++nt) {
            int n = wave * 32 + nt * 16 + l15;
            short8 b = *(const short8*)(Wot + n * HID + ko);
            #pragma unroll
            for (int mt = 0; mt < 4; ++mt)
                acc[mt][nt] = __builtin_amdgcn_mfma_f32_16x16x32_bf16(a[mt], b, acc[mt][nt], 0, 0, 0);
        }
    }
    __syncthreads();   // all reads of A2 done (also guards in-place write ordering)

    #pragma unroll
    for (int nt = 0; nt < 2; ++nt) {
        int col = wave * 32 + nt * 16 + l15;
        float bias = bo[col];
        #pragma unroll
        for (int mt = 0; mt < 4; ++mt) {
            #pragma unroll
            for (int r = 0; r < 4; ++r) {
                int row = mt * 16 + quad * 4 + r;
                int node = n0 + row;
                if (node < NN)
                    out[(size_t)node * HID + col] = acc[mt][nt][r] + bias;
            }
        }
    }
}

extern "C" void kernel_launch(void* const* d_in, const int* in_sizes, int n_in,
                              void* d_out, int out_size, void* d_ws, size_t ws_size,
                              hipStream_t stream) {
    const float* nf  = (const float*)d_in[0];
    const float* pos = (const float*)d_in[1];
    const int*   ei  = (const int*)d_in[2];
    const float* W1  = (const float*)d_in[3];
    const float* b1  = (const float*)d_in[4];
    const float* W2  = (const float*)d_in[5];
    const float* b2  = (const float*)d_in[6];
    const float* Wo  = (const float*)d_in[7];
    const float* bo  = (const float*)d_in[8];
    float* out = (float*)d_out;

    char* ws = (char*)d_ws;
    short* nfb      = (short*)(ws);                 // 12,800,000
    short* W1t      = (short*)(ws + 12800000);      //     73,728
    short* W2t      = (short*)(ws + 12873728);      //     32,768
    short* Wot      = (short*)(ws + 12906496);      //     32,768
    int*   counts   = (int*)(ws + 12939264);        //    200,704
    int*   scanEx   = (int*)(ws + 13139968);        //    200,704
    int*   blockSum = (int*)(ws + 13340672);        //      1,024
    int*   blockBase= (int*)(ws + 13341696);        //      1,024
    int*   nodeBase = (int*)(ws + 13342720);        //    200,704
    int*   cursor   = (int*)(ws + 13543424);        //    200,704
    int*   srcS     = (int*)(ws + 13744128);        //  3,200,000
    int*   dstS     = (int*)(ws + 16944128);        //  3,200,000  -> total 20,144,128

    hipMemsetAsync(out, 0, (size_t)NN * HID * sizeof(float), stream);
    hipMemsetAsync(counts, 0, 200704, stream);

    prep_nf<<<3125, 256, 0, stream>>>(nf, nfb);
    prep_w<<<272, 256, 0, stream>>>(W1, W2, Wo, W1t, W2t, Wot);

    k_hist<<<3125, 256, 0, stream>>>(ei + NE, counts);
    k_scan1<<<SCAN_B, 256, 0, stream>>>(counts, scanEx, blockSum);
    k_scan2<<<1, 256, 0, stream>>>(blockSum, blockBase);
    k_scan3<<<SCAN_B, 256, 0, stream>>>(scanEx, blockBase, nodeBase, cursor);
    k_permute<<<3125, 256, 0, stream>>>(ei, ei + NE, nodeBase, cursor, srcS, dstS);

    edge_kernel<<<NE / 64, 256, 0, stream>>>(nfb, pos, srcS, dstS,
                                             W1t, b1, W2t, b2, out);
    out_kernel<<<(NN + 63) / 64, 256, 0, stream>>>(out, counts, Wot, bo);
}

// Round 3
// 470.368 us; speedup vs baseline: 1.3023x; 1.1148x over previous
//
#include <hip/hip_runtime.h>
#include <hip/hip_bf16.h>

#define NN 50000
#define NE 800000
#define HID 128
#define NB 32
#define EIN 288   // 2*HID + NB

typedef short short8 __attribute__((ext_vector_type(8)));
typedef float f32x4 __attribute__((ext_vector_type(4)));

static __device__ __forceinline__ short f2bf(float x) {
    unsigned int u = __float_as_uint(x);
    unsigned int r = (u + 0x7fffu + ((u >> 16) & 1u)) >> 16;
    return (short)r;
}

// ---- fused prep: nf fp32->bf16 + dst histogram (blocks < 3125), weight transpose (rest) ----
__global__ void fused_prep(const float* __restrict__ nf, short* __restrict__ nfb,
                           const int* __restrict__ dstI, int* __restrict__ counts,
                           const float* __restrict__ W1, const float* __restrict__ W2,
                           const float* __restrict__ Wo,
                           short* __restrict__ W1t, short* __restrict__ W2t,
                           short* __restrict__ Wot) {
    int b = blockIdx.x;
    if (b < 3125) {
        int i = b * 256 + threadIdx.x;           // 800000 threads
        const float4* sp = (const float4*)nf + (size_t)i * 2;
        float4 a = sp[0], c = sp[1];
        short8 o;
        o[0] = f2bf(a.x); o[1] = f2bf(a.y); o[2] = f2bf(a.z); o[3] = f2bf(a.w);
        o[4] = f2bf(c.x); o[5] = f2bf(c.y); o[6] = f2bf(c.z); o[7] = f2bf(c.w);
        *((short8*)nfb + i) = o;
        atomicAdd(&counts[dstI[i]], 1);
    } else {
        int t = (b - 3125) * 256 + threadIdx.x;  // 0..69631
        if (t < EIN * HID) {
            int n = t / EIN, k = t % EIN;
            W1t[t] = f2bf(W1[k * HID + n]);
        } else if ((t -= EIN * HID) < HID * HID) {
            int n = t / HID, k = t % HID;
            W2t[t] = f2bf(W2[k * HID + n]);
        } else if ((t -= HID * HID) < HID * HID) {
            int n = t / HID, k = t % HID;
            Wot[t] = f2bf(Wo[k * HID + n]);
        }
    }
}

// ---- single-block exclusive scan of counts -> cur (cursor initialized to node base) ----
#define CHUNK 49   // 1024*49 = 50176 >= NN
__global__ void k_scan(const int* __restrict__ counts, int* __restrict__ cur) {
    __shared__ int part[1024];
    int t = threadIdx.x;
    int base = t * CHUNK;
    int s = 0;
    #pragma unroll 7
    for (int i = 0; i < CHUNK; ++i) {
        int idx = base + i;
        s += (idx < NN) ? counts[idx] : 0;
    }
    part[t] = s;
    __syncthreads();
    #pragma unroll
    for (int off = 1; off < 1024; off <<= 1) {
        int x = (t >= off) ? part[t - off] : 0;
        __syncthreads();
        part[t] += x;
        __syncthreads();
    }
    int run = part[t] - s;   // exclusive prefix of this chunk
    #pragma unroll 7
    for (int i = 0; i < CHUNK; ++i) {
        int idx = base + i;
        if (idx < NN) {
            cur[idx] = run;
            run += counts[idx];
        }
    }
}

// ---- permute edges into dst-sorted order (packed int2) ----
__global__ void k_permute(const int* __restrict__ src, const int* __restrict__ dst,
                          int* __restrict__ cur, int2* __restrict__ edgeS) {
    int e = blockIdx.x * 256 + threadIdx.x;
    int s = src[e];
    int d = dst[e];
    int r = atomicAdd(&cur[d], 1);
    edgeS[r] = make_int2(s, d);
}

// ---- fused edge MLP + tile-merged scatter (edges sorted by dst) ----
// 128 edges/block, 512 threads = 8 waves (2 M-groups x 4 N-slices).
// LDS U reused across phases: As[128,296] -> Ps[128,136] -> fp32 out [128,132].
__launch_bounds__(512, 4)
__global__ void edge_kernel(const short* __restrict__ nfb,
                            const float* __restrict__ pos,
                            const int2* __restrict__ edgeS,
                            const short* __restrict__ W1t,
                            const float* __restrict__ b1,
                            const short* __restrict__ W2t,
                            const float* __restrict__ b2,
                            float* __restrict__ upd) {
    __shared__ short U[128 * 296];   // 75,776 B
    __shared__ int   dn_sh[128];
    float* Uf = (float*)U;           // fp32 phase: [128,132]

    const int tid  = threadIdx.x;
    const int wave = tid >> 6;
    const int lane = tid & 63;
    const int quad = lane >> 4;
    const int l15  = lane & 15;
    const int mg   = wave >> 2;      // M-group: rows [mg*64, mg*64+64)
    const int nsl  = wave & 3;       // N-slice: cols [nsl*32, nsl*32+32)
    const int e0   = blockIdx.x * 128;

    // ---- stage: gather node rows + RBF ----
    {
        int es = tid >> 2;           // 0..127 edge in tile
        int pt = tid & 3;            // 32-col slice
        int2 sd = edgeS[e0 + es];
        int s = sd.x, d = sd.y;
        const int4* sp = (const int4*)(nfb + (size_t)s * HID + pt * 32);
        const int4* dp = (const int4*)(nfb + (size_t)d * HID + pt * 32);
        int4* as = (int4*)(U + es * 296 + pt * 32);
        int4* ad = (int4*)(U + es * 296 + 128 + pt * 32);
        #pragma unroll
        for (int j = 0; j < 4; ++j) as[j] = sp[j];
        #pragma unroll
        for (int j = 0; j < 4; ++j) ad[j] = dp[j];
        if (pt == 0) dn_sh[es] = d;
        float dx = pos[d * 3 + 0] - pos[s * 3 + 0];
        float dy = pos[d * 3 + 1] - pos[s * 3 + 1];
        float dz = pos[d * 3 + 2] - pos[s * 3 + 2];
        float dd = fminf(sqrtf(dx * dx + dy * dy + dz * dz), 5.0f);
        const float step  = 5.0f / 31.0f;
        const float width = 0.5f * (step + 0.01f);
        const float coef  = -0.5f / (width * width);
        short8 r;
        #pragma unroll
        for (int j = 0; j < 8; ++j) {
            float c = step * (float)(pt * 8 + j);
            float t = dd - c;
            r[j] = f2bf(__expf(coef * t * t));
        }
        *(short8*)(U + es * 296 + 256 + pt * 8) = r;
    }
    __syncthreads();

    // ---- layer 1: [128x288] @ [288x128] ----
    f32x4 acc[4][2];
    #pragma unroll
    for (int mt = 0; mt < 4; ++mt)
        #pragma unroll
        for (int nt = 0; nt < 2; ++nt) acc[mt][nt] = (f32x4){0.f, 0.f, 0.f, 0.f};

    #pragma unroll
    for (int kk = 0; kk < 9; ++kk) {
        int ko = kk * 32 + quad * 8;
        short8 a[4];
        #pragma unroll
        for (int mt = 0; mt < 4; ++mt)
            a[mt] = *(const short8*)(U + (mg * 64 + mt * 16 + l15) * 296 + ko);
        #pragma unroll
        for (int nt = 0; nt < 2; ++nt) {
            int n = nsl * 32 + nt * 16 + l15;
            short8 b = *(const short8*)(W1t + n * EIN + ko);
            #pragma unroll
            for (int mt = 0; mt < 4; ++mt)
                acc[mt][nt] = __builtin_amdgcn_mfma_f32_16x16x32_bf16(a[mt], b, acc[mt][nt], 0, 0, 0);
        }
    }
    __syncthreads();   // As reads done before Ps overwrites

    // ---- bias + SiLU -> Ps [128,136] ----
    #pragma unroll
    for (int nt = 0; nt < 2; ++nt) {
        int col = nsl * 32 + nt * 16 + l15;
        float bias = b1[col];
        #pragma unroll
        for (int mt = 0; mt < 4; ++mt) {
            #pragma unroll
            for (int r = 0; r < 4; ++r) {
                int row = mg * 64 + mt * 16 + quad * 4 + r;
                float x = acc[mt][nt][r] + bias;
                float p = x / (1.0f + __expf(-x));
                U[row * 136 + col] = f2bf(p);
            }
        }
    }
    __syncthreads();

    // ---- layer 2: [128x128] @ [128x128] ----
    f32x4 acc2[4][2];
    #pragma unroll
    for (int mt = 0; mt < 4; ++mt)
        #pragma unroll
        for (int nt = 0; nt < 2; ++nt) acc2[mt][nt] = (f32x4){0.f, 0.f, 0.f, 0.f};

    #pragma unroll
    for (int kk = 0; kk < 4; ++kk) {
        int ko = kk * 32 + quad * 8;
        short8 a[4];
        #pragma unroll
        for (int mt = 0; mt < 4; ++mt)
            a[mt] = *(const short8*)(U + (mg * 64 + mt * 16 + l15) * 136 + ko);
        #pragma unroll
        for (int nt = 0; nt < 2; ++nt) {
            int n = nsl * 32 + nt * 16 + l15;
            short8 b = *(const short8*)(W2t + n * HID + ko);
            #pragma unroll
            for (int mt = 0; mt < 4; ++mt)
                acc2[mt][nt] = __builtin_amdgcn_mfma_f32_16x16x32_bf16(a[mt], b, acc2[mt][nt], 0, 0, 0);
        }
    }
    __syncthreads();   // Ps reads done before fp32 overwrite

    // ---- bias -> fp32 LDS [128,132] ----
    #pragma unroll
    for (int nt = 0; nt < 2; ++nt) {
        int col = nsl * 32 + nt * 16 + l15;
        float bias = b2[col];
        #pragma unroll
        for (int mt = 0; mt < 4; ++mt) {
            #pragma unroll
            for (int r = 0; r < 4; ++r) {
                int row = mg * 64 + mt * 16 + quad * 4 + r;
                Uf[row * 132 + col] = acc2[mt][nt][r] + bias;
            }
        }
    }
    __syncthreads();

    // ---- tile-level run merge + scatter. Wave-uniform rows: tid>>7 = segment. ----
    {
        int col = tid & 127;
        int r0  = (tid >> 7) * 32;
        int rnode = dn_sh[r0];
        float run = 0.0f;
        #pragma unroll
        for (int r = 0; r < 32; ++r) {
            int node = dn_sh[r0 + r];
            float v = Uf[(r0 + r) * 132 + col];
            if (node != rnode) {
                atomicAdd(upd + (size_t)rnode * HID + col, run);
                rnode = node;
                run = v;
            } else {
                run += v;
            }
        }
        atomicAdd(upd + (size_t)rnode * HID + col, run);
    }
}

// ---- normalize by degree + @Wo + bo (MFMA), in place on d_out ----
__launch_bounds__(256, 4)
__global__ void out_kernel(float* __restrict__ out,
                           const int* __restrict__ counts,
                           const short* __restrict__ Wot,
                           const float* __restrict__ bo) {
    __shared__ short A2[64 * 136];

    const int tid  = threadIdx.x;
    const int wave = tid >> 6;
    const int lane = tid & 63;
    const int quad = lane >> 4;
    const int l15  = lane & 15;
    const int n0   = blockIdx.x * 64;

    {
        int row = tid >> 2, pt = tid & 3;
        int node = n0 + row;
        if (node < NN) {
            float inv = 1.0f / fmaxf((float)counts[node], 1.0f);
            const float4* p = (const float4*)(out + (size_t)node * HID + pt * 32);
            #pragma unroll
            for (int j = 0; j < 4; ++j) {
                float4 w0 = p[j * 2], w1 = p[j * 2 + 1];
                short8 o;
                o[0] = f2bf(w0.x * inv); o[1] = f2bf(w0.y * inv);
                o[2] = f2bf(w0.z * inv); o[3] = f2bf(w0.w * inv);
                o[4] = f2bf(w1.x * inv); o[5] = f2bf(w1.y * inv);
                o[6] = f2bf(w1.z * inv); o[7] = f2bf(w1.w * inv);
                *(short8*)(A2 + row * 136 + pt * 32 + j * 8) = o;
            }
        } else {
            short8 z = (short8){0, 0, 0, 0, 0, 0, 0, 0};
            #pragma unroll
            for (int j = 0; j < 4; ++j)
                *(short8*)(A2 + row * 136 + pt * 32 + j * 8) = z;
        }
    }
    __syncthreads();

    f32x4 acc[4][2];
    #pragma unroll
    for (int mt = 0; mt < 4; ++mt)
        #pragma unroll
        for (int nt = 0; nt < 2; ++nt) acc[mt][nt] = (f32x4){0.f, 0.f, 0.f, 0.f};

    #pragma unroll
    for (int kk = 0; kk < 4; ++kk) {
        int ko = kk * 32 + quad * 8;
        short8 a[4];
        #pragma unroll
        for (int mt = 0; mt < 4; ++mt)
            a[mt] = *(const short8*)(A2 + (mt * 16 + l15) * 136 + ko);
        #pragma unroll
        for (int nt = 0; nt < 2; ++nt) {
            int n = wave * 32 + nt * 16 + l15;
            short8 b = *(const short8*)(Wot + n * HID + ko);
            #pragma unroll
            for (int mt = 0; mt < 4; ++mt)
                acc[mt][nt] = __builtin_amdgcn_mfma_f32_16x16x32_bf16(a[mt], b, acc[mt][nt], 0, 0, 0);
        }
    }
    __syncthreads();

    #pragma unroll
    for (int nt = 0; nt < 2; ++nt) {
        int col = wave * 32 + nt * 16 + l15;
        float bias = bo[col];
        #pragma unroll
        for (int mt = 0; mt < 4; ++mt) {
            #pragma unroll
            for (int r = 0; r < 4; ++r) {
                int row = mt * 16 + quad * 4 + r;
                int node = n0 + row;
                if (node < NN)
                    out[(size_t)node * HID + col] = acc[mt][nt][r] + bias;
            }
        }
    }
}

extern "C" void kernel_launch(void* const* d_in, const int* in_sizes, int n_in,
                              void* d_out, int out_size, void* d_ws, size_t ws_size,
                              hipStream_t stream) {
    const float* nf  = (const float*)d_in[0];
    const float* pos = (const float*)d_in[1];
    const int*   ei  = (const int*)d_in[2];
    const float* W1  = (const float*)d_in[3];
    const float* b1  = (const float*)d_in[4];
    const float* W2  = (const float*)d_in[5];
    const float* b2  = (const float*)d_in[6];
    const float* Wo  = (const float*)d_in[7];
    const float* bo  = (const float*)d_in[8];
    float* out = (float*)d_out;

    char* ws = (char*)d_ws;
    short* nfb    = (short*)(ws);                 // 12,800,000
    short* W1t    = (short*)(ws + 12800000);      //     73,728
    short* W2t    = (short*)(ws + 12873728);      //     32,768
    short* Wot    = (short*)(ws + 12906496);      //     32,768
    int*   counts = (int*)(ws + 12939264);        //    200,704
    int*   cur    = (int*)(ws + 13139968);        //    200,704
    int2*  edgeS  = (int2*)(ws + 13340672);       //  6,400,000  -> total 19,740,672

    hipMemsetAsync(out, 0, (size_t)NN * HID * sizeof(float), stream);
    hipMemsetAsync(counts, 0, 200704, stream);

    fused_prep<<<3397, 256, 0, stream>>>(nf, nfb, ei + NE, counts,
                                         W1, W2, Wo, W1t, W2t, Wot);
    k_scan<<<1, 1024, 0, stream>>>(counts, cur);
    k_permute<<<3125, 256, 0, stream>>>(ei, ei + NE, cur, edgeS);
    edge_kernel<<<NE / 128, 512, 0, stream>>>(nfb, pos, edgeS,
                                              W1t, b1, W2t, b2, out);
    out_kernel<<<(NN + 63) / 64, 256, 0, stream>>>(out, counts, Wot, bo);
}

// Round 4
// 345.819 us; speedup vs baseline: 1.7713x; 1.3602x over previous
//
#include <hip/hip_runtime.h>

#define NN 50000
#define NE 800000
#define HID 128
#define NB 32
#define SCAN_B 196   // 196*256 = 50176 >= NN

typedef short short8 __attribute__((ext_vector_type(8)));
typedef float f32x4 __attribute__((ext_vector_type(4)));

static __device__ __forceinline__ short f2bf(float x) {
    unsigned int u = __float_as_uint(x);
    unsigned int r = (u + 0x7fffu + ((u >> 16) & 1u)) >> 16;
    return (short)r;
}

// add two packed bf16 pairs in fp32, repack (RNE)
static __device__ __forceinline__ unsigned int addpack(unsigned int a, unsigned int b) {
    float lo = __uint_as_float(a << 16) + __uint_as_float(b << 16);
    float hi = __uint_as_float(a & 0xffff0000u) + __uint_as_float(b & 0xffff0000u);
    return ((unsigned int)(unsigned short)f2bf(hi) << 16) | (unsigned short)f2bf(lo);
}

// ---- prep: dst histogram (blocks < 3125) + weight transposes (272 blocks) ----
__global__ void fused_prep(const int* __restrict__ dstI, int* __restrict__ counts,
                           const float* __restrict__ W1, const float* __restrict__ W2,
                           const float* __restrict__ Wo,
                           short* __restrict__ W1aT, short* __restrict__ W1bT,
                           short* __restrict__ W1cT, short* __restrict__ W2t,
                           short* __restrict__ Wot) {
    int b = blockIdx.x;
    if (b < 3125) {
        int e = b * 256 + threadIdx.x;
        atomicAdd(&counts[dstI[e]], 1);
    } else {
        int t = (b - 3125) * 256 + threadIdx.x;   // 0..69631
        if (t < 16384) {
            int n = t >> 7, k = t & 127;
            W1aT[t] = f2bf(W1[k * HID + n]);
        } else if ((t -= 16384) < 16384) {
            int n = t >> 7, k = t & 127;
            W1bT[t] = f2bf(W1[(k + 128) * HID + n]);
        } else if ((t -= 16384) < 4096) {
            int n = t >> 5, k = t & 31;
            W1cT[t] = f2bf(W1[(k + 256) * HID + n]);
        } else if ((t -= 4096) < 16384) {
            int n = t >> 7, k = t & 127;
            W2t[t] = f2bf(W2[k * HID + n]);
        } else if ((t -= 16384) < 16384) {
            int n = t >> 7, k = t & 127;
            Wot[t] = f2bf(Wo[k * HID + n]);
        }
    }
}

// ---- parallel 3-kernel scan (cursor-fused) ----
__global__ void k_scan1(const int* __restrict__ counts, int* __restrict__ scanEx,
                        int* __restrict__ blockSum) {
    __shared__ int s[256];
    int t = threadIdx.x, idx = blockIdx.x * 256 + t;
    int v = counts[idx];   // counts buffer sized 50176, zeroed
    s[t] = v; __syncthreads();
    #pragma unroll
    for (int off = 1; off < 256; off <<= 1) {
        int x = (t >= off) ? s[t - off] : 0;
        __syncthreads();
        s[t] += x;
        __syncthreads();
    }
    scanEx[idx] = s[t] - v;
    if (t == 255) blockSum[blockIdx.x] = s[255];
}

__global__ void k_scan2(const int* __restrict__ blockSum, int* __restrict__ blockBase) {
    __shared__ int s[256];
    int t = threadIdx.x;
    int v = (t < SCAN_B) ? blockSum[t] : 0;
    s[t] = v; __syncthreads();
    #pragma unroll
    for (int off = 1; off < 256; off <<= 1) {
        int x = (t >= off) ? s[t - off] : 0;
        __syncthreads();
        s[t] += x;
        __syncthreads();
    }
    blockBase[t] = s[t] - v;
}

__global__ void k_scan3(const int* __restrict__ scanEx, const int* __restrict__ blockBase,
                        int* __restrict__ cur) {
    int idx = blockIdx.x * 256 + threadIdx.x;
    cur[idx] = scanEx[idx] + blockBase[blockIdx.x];
}

__global__ void k_permute(const int* __restrict__ src, const int* __restrict__ dst,
                          int* __restrict__ cur, int2* __restrict__ edgeS) {
    int e = blockIdx.x * 256 + threadIdx.x;
    int s = src[e];
    int d = dst[e];
    int r = atomicAdd(&cur[d], 1);
    edgeS[r] = make_int2(s, d);
}

// ---- per-node precompute: S = nf@W1a, D = nf@W1b (bf16 out) ----
__global__ void sd_kernel(const float* __restrict__ nf,
                          const short* __restrict__ W1aT, const short* __restrict__ W1bT,
                          short* __restrict__ Sg, short* __restrict__ Dg) {
    __shared__ short As[64 * 136];
    const int tid  = threadIdx.x;
    const int wave = tid >> 6;     // n-slice
    const int lane = tid & 63;
    const int quad = lane >> 4;
    const int l15  = lane & 15;
    const int n0   = blockIdx.x * 64;

    {
        int row = tid >> 2, pt = tid & 3;
        int node = min(n0 + row, NN - 1);
        const float4* p = (const float4*)(nf + (size_t)node * HID + pt * 32);
        #pragma unroll
        for (int j = 0; j < 4; ++j) {
            float4 w0 = p[j * 2], w1 = p[j * 2 + 1];
            short8 o;
            o[0] = f2bf(w0.x); o[1] = f2bf(w0.y); o[2] = f2bf(w0.z); o[3] = f2bf(w0.w);
            o[4] = f2bf(w1.x); o[5] = f2bf(w1.y); o[6] = f2bf(w1.z); o[7] = f2bf(w1.w);
            *(short8*)(As + row * 136 + pt * 32 + j * 8) = o;
        }
    }
    __syncthreads();

    f32x4 aS[4][2], aD[4][2];
    #pragma unroll
    for (int mt = 0; mt < 4; ++mt)
        #pragma unroll
        for (int nt = 0; nt < 2; ++nt) {
            aS[mt][nt] = (f32x4){0.f, 0.f, 0.f, 0.f};
            aD[mt][nt] = (f32x4){0.f, 0.f, 0.f, 0.f};
        }

    #pragma unroll
    for (int kk = 0; kk < 4; ++kk) {
        int ko = kk * 32 + quad * 8;
        short8 a[4];
        #pragma unroll
        for (int mt = 0; mt < 4; ++mt)
            a[mt] = *(const short8*)(As + (mt * 16 + l15) * 136 + ko);
        #pragma unroll
        for (int nt = 0; nt < 2; ++nt) {
            int n = wave * 32 + nt * 16 + l15;
            short8 bS = *(const short8*)(W1aT + n * HID + ko);
            short8 bD = *(const short8*)(W1bT + n * HID + ko);
            #pragma unroll
            for (int mt = 0; mt < 4; ++mt) {
                aS[mt][nt] = __builtin_amdgcn_mfma_f32_16x16x32_bf16(a[mt], bS, aS[mt][nt], 0, 0, 0);
                aD[mt][nt] = __builtin_amdgcn_mfma_f32_16x16x32_bf16(a[mt], bD, aD[mt][nt], 0, 0, 0);
            }
        }
    }

    #pragma unroll
    for (int nt = 0; nt < 2; ++nt) {
        int col = wave * 32 + nt * 16 + l15;
        #pragma unroll
        for (int mt = 0; mt < 4; ++mt) {
            #pragma unroll
            for (int r = 0; r < 4; ++r) {
                int node = n0 + mt * 16 + quad * 4 + r;
                if (node < NN) {
                    Sg[(size_t)node * HID + col] = f2bf(aS[mt][nt][r]);
                    Dg[(size_t)node * HID + col] = f2bf(aD[mt][nt][r]);
                }
            }
        }
    }
}

// ---- fused edge MLP + tile-merged scatter (edges sorted by dst) ----
// 128 edges/block, 512 threads. Layer1 = rbf@W1c (K=32) + gathered PRE=S[src]+D[dst].
// LDS union 48 KB + dn -> 3 blocks/CU.
__launch_bounds__(512, 6)
__global__ void edge_kernel(const short* __restrict__ Sg,
                            const short* __restrict__ Dg,
                            const float* __restrict__ pos,
                            const int2* __restrict__ edgeS,
                            const short* __restrict__ W1cT,
                            const float* __restrict__ b1,
                            const short* __restrict__ W2t,
                            const float* __restrict__ b2,
                            float* __restrict__ upd) {
    __shared__ char buf[49152];
    __shared__ int  dn_sh[128];
    short* PRE = (short*)buf;              // [128][136] bf16: S[src]+D[dst]
    short* R   = (short*)(buf + 34816);    // [128][56]  bf16 rbf
    short* Ps  = (short*)buf;              // [128][136] (in-place after PRE consumed)
    float* UfT = (float*)buf;              // [128 cols][68] fp32, one 64-row half

    const int tid  = threadIdx.x;
    const int wave = tid >> 6;
    const int lane = tid & 63;
    const int quad = lane >> 4;
    const int l15  = lane & 15;
    const int mg   = wave >> 2;       // row half: [mg*64, mg*64+64)
    const int nsl  = wave & 3;        // col slice: [nsl*32, nsl*32+32)
    const int e0   = blockIdx.x * 128;

    // ---- stage: PRE = S[src]+D[dst] (bf16), RBF tile, dst ids ----
    {
        int es = tid >> 2, pt = tid & 3;
        int2 sd = edgeS[e0 + es];
        int s = sd.x, d = sd.y;
        const int4* sp = (const int4*)(Sg + (size_t)s * HID + pt * 32);
        const int4* dp = (const int4*)(Dg + (size_t)d * HID + pt * 32);
        int4* op = (int4*)(PRE + es * 136 + pt * 32);
        #pragma unroll
        for (int j = 0; j < 4; ++j) {
            int4 a = sp[j], b = dp[j];
            int4 o;
            o.x = addpack(a.x, b.x);
            o.y = addpack(a.y, b.y);
            o.z = addpack(a.z, b.z);
            o.w = addpack(a.w, b.w);
            op[j] = o;
        }
        if (pt == 0) dn_sh[es] = d;
        float dx = pos[d * 3 + 0] - pos[s * 3 + 0];
        float dy = pos[d * 3 + 1] - pos[s * 3 + 1];
        float dz = pos[d * 3 + 2] - pos[s * 3 + 2];
        float dd = fminf(sqrtf(dx * dx + dy * dy + dz * dz), 5.0f);
        const float step  = 5.0f / 31.0f;
        const float width = 0.5f * (step + 0.01f);
        const float coef  = -0.5f / (width * width);
        short8 r;
        #pragma unroll
        for (int j = 0; j < 8; ++j) {
            float c = step * (float)(pt * 8 + j);
            float t = dd - c;
            r[j] = f2bf(__expf(coef * t * t));
        }
        *(short8*)(R + es * 56 + pt * 8) = r;
    }
    __syncthreads();

    // ---- layer 1: rbf [128x32] @ W1c [32x128], single K-step ----
    f32x4 acc[4][2];
    #pragma unroll
    for (int mt = 0; mt < 4; ++mt)
        #pragma unroll
        for (int nt = 0; nt < 2; ++nt) acc[mt][nt] = (f32x4){0.f, 0.f, 0.f, 0.f};
    {
        int ko = quad * 8;
        short8 a[4];
        #pragma unroll
        for (int mt = 0; mt < 4; ++mt)
            a[mt] = *(const short8*)(R + (mg * 64 + mt * 16 + l15) * 56 + ko);
        #pragma unroll
        for (int nt = 0; nt < 2; ++nt) {
            int n = nsl * 32 + nt * 16 + l15;
            short8 b = *(const short8*)(W1cT + n * NB + ko);
            #pragma unroll
            for (int mt = 0; mt < 4; ++mt)
                acc[mt][nt] = __builtin_amdgcn_mfma_f32_16x16x32_bf16(a[mt], b, acc[mt][nt], 0, 0, 0);
        }
    }

    // ---- + PRE + b1, SiLU -> Ps in place (per-thread read/write addr sets identical & disjoint) ----
    {
        float b1c[2] = { b1[nsl * 32 + l15], b1[nsl * 32 + 16 + l15] };
        const unsigned short* PREu = (const unsigned short*)PRE;
        #pragma unroll
        for (int nt = 0; nt < 2; ++nt) {
            int col = nsl * 32 + nt * 16 + l15;
            #pragma unroll
            for (int mt = 0; mt < 4; ++mt) {
                #pragma unroll
                for (int r = 0; r < 4; ++r) {
                    int row = mg * 64 + mt * 16 + quad * 4 + r;
                    float pre = __uint_as_float((unsigned int)PREu[row * 136 + col] << 16);
                    float x = acc[mt][nt][r] + pre + b1c[nt];
                    float p = x / (1.0f + __expf(-x));
                    Ps[row * 136 + col] = f2bf(p);
                }
            }
        }
    }
    __syncthreads();

    // ---- layer 2: [128x128] @ [128x128] ----
    f32x4 acc2[4][2];
    #pragma unroll
    for (int mt = 0; mt < 4; ++mt)
        #pragma unroll
        for (int nt = 0; nt < 2; ++nt) acc2[mt][nt] = (f32x4){0.f, 0.f, 0.f, 0.f};

    #pragma unroll
    for (int kk = 0; kk < 4; ++kk) {
        int ko = kk * 32 + quad * 8;
        short8 a[4];
        #pragma unroll
        for (int mt = 0; mt < 4; ++mt)
            a[mt] = *(const short8*)(Ps + (mg * 64 + mt * 16 + l15) * 136 + ko);
        #pragma unroll
        for (int nt = 0; nt < 2; ++nt) {
            int n = nsl * 32 + nt * 16 + l15;
            short8 b = *(const short8*)(W2t + n * HID + ko);
            #pragma unroll
            for (int mt = 0; mt < 4; ++mt)
                acc2[mt][nt] = __builtin_amdgcn_mfma_f32_16x16x32_bf16(a[mt], b, acc2[mt][nt], 0, 0, 0);
        }
    }
    __syncthreads();   // Ps reads done before UfT overwrites

    // ---- two 64-row halves: transposed fp32 buffer + merged scatter ----
    float b2c[2] = { b2[nsl * 32 + l15], b2[nsl * 32 + 16 + l15] };
    #pragma unroll
    for (int h = 0; h < 2; ++h) {
        if (mg == h) {
            #pragma unroll
            for (int nt = 0; nt < 2; ++nt) {
                int col = nsl * 32 + nt * 16 + l15;
                #pragma unroll
                for (int mt = 0; mt < 4; ++mt) {
                    f32x4 v;
                    #pragma unroll
                    for (int r = 0; r < 4; ++r) v[r] = acc2[mt][nt][r] + b2c[nt];
                    *(f32x4*)(UfT + col * 68 + mt * 16 + quad * 4) = v;
                }
            }
        }
        __syncthreads();
        {
            int col = tid & 127;
            int seg = tid >> 7;            // 4 segments x 16 rows
            int rb  = h * 64 + seg * 16;
            const float* cp = UfT + col * 68 + seg * 16;
            f32x4 vv[4];
            #pragma unroll
            for (int j = 0; j < 4; ++j) vv[j] = *(const f32x4*)(cp + j * 4);
            int rnode = dn_sh[rb];
            float run = 0.0f;
            #pragma unroll
            for (int i = 0; i < 16; ++i) {
                int node = dn_sh[rb + i];
                float v = vv[i >> 2][i & 3];
                if (node != rnode) {
                    atomicAdd(upd + (size_t)rnode * HID + col, run);
                    rnode = node;
                    run = v;
                } else {
                    run += v;
                }
            }
            atomicAdd(upd + (size_t)rnode * HID + col, run);
        }
        __syncthreads();
    }
}

// ---- normalize by degree + @Wo + bo (MFMA), in place on d_out ----
__launch_bounds__(256, 4)
__global__ void out_kernel(float* __restrict__ out,
                           const int* __restrict__ counts,
                           const short* __restrict__ Wot,
                           const float* __restrict__ bo) {
    __shared__ short A2[64 * 136];

    const int tid  = threadIdx.x;
    const int wave = tid >> 6;
    const int lane = tid & 63;
    const int quad = lane >> 4;
    const int l15  = lane & 15;
    const int n0   = blockIdx.x * 64;

    {
        int row = tid >> 2, pt = tid & 3;
        int node = n0 + row;
        if (node < NN) {
            float inv = 1.0f / fmaxf((float)counts[node], 1.0f);
            const float4* p = (const float4*)(out + (size_t)node * HID + pt * 32);
            #pragma unroll
            for (int j = 0; j < 4; ++j) {
                float4 w0 = p[j * 2], w1 = p[j * 2 + 1];
                short8 o;
                o[0] = f2bf(w0.x * inv); o[1] = f2bf(w0.y * inv);
                o[2] = f2bf(w0.z * inv); o[3] = f2bf(w0.w * inv);
                o[4] = f2bf(w1.x * inv); o[5] = f2bf(w1.y * inv);
                o[6] = f2bf(w1.z * inv); o[7] = f2bf(w1.w * inv);
                *(short8*)(A2 + row * 136 + pt * 32 + j * 8) = o;
            }
        } else {
            short8 z = (short8){0, 0, 0, 0, 0, 0, 0, 0};
            #pragma unroll
            for (int j = 0; j < 4; ++j)
                *(short8*)(A2 + row * 136 + pt * 32 + j * 8) = z;
        }
    }
    __syncthreads();

    f32x4 acc[4][2];
    #pragma unroll
    for (int mt = 0; mt < 4; ++mt)
        #pragma unroll
        for (int nt = 0; nt < 2; ++nt) acc[mt][nt] = (f32x4){0.f, 0.f, 0.f, 0.f};

    #pragma unroll
    for (int kk = 0; kk < 4; ++kk) {
        int ko = kk * 32 + quad * 8;
        short8 a[4];
        #pragma unroll
        for (int mt = 0; mt < 4; ++mt)
            a[mt] = *(const short8*)(A2 + (mt * 16 + l15) * 136 + ko);
        #pragma unroll
        for (int nt = 0; nt < 2; ++nt) {
            int n = wave * 32 + nt * 16 + l15;
            short8 b = *(const short8*)(Wot + n * HID + ko);
            #pragma unroll
            for (int mt = 0; mt < 4; ++mt)
                acc[mt][nt] = __builtin_amdgcn_mfma_f32_16x16x32_bf16(a[mt], b, acc[mt][nt], 0, 0, 0);
        }
    }
    __syncthreads();

    #pragma unroll
    for (int nt = 0; nt < 2; ++nt) {
        int col = wave * 32 + nt * 16 + l15;
        float bias = bo[col];
        #pragma unroll
        for (int mt = 0; mt < 4; ++mt) {
            #pragma unroll
            for (int r = 0; r < 4; ++r) {
                int row = mt * 16 + quad * 4 + r;
                int node = n0 + row;
                if (node < NN)
                    out[(size_t)node * HID + col] = acc[mt][nt][r] + bias;
            }
        }
    }
}

extern "C" void kernel_launch(void* const* d_in, const int* in_sizes, int n_in,
                              void* d_out, int out_size, void* d_ws, size_t ws_size,
                              hipStream_t stream) {
    const float* nf  = (const float*)d_in[0];
    const float* pos = (const float*)d_in[1];
    const int*   ei  = (const int*)d_in[2];
    const float* W1  = (const float*)d_in[3];
    const float* b1  = (const float*)d_in[4];
    const float* W2  = (const float*)d_in[5];
    const float* b2  = (const float*)d_in[6];
    const float* Wo  = (const float*)d_in[7];
    const float* bo  = (const float*)d_in[8];
    float* out = (float*)d_out;

    char* ws = (char*)d_ws;
    short* W1aT     = (short*)(ws);                 //     32,768
    short* W1bT     = (short*)(ws + 32768);         //     32,768
    short* W1cT     = (short*)(ws + 65536);         //      8,192
    short* W2t      = (short*)(ws + 73728);         //     32,768
    short* Wot      = (short*)(ws + 106496);        //     32,768
    int*   counts   = (int*)(ws + 139264);          //    200,704
    int*   scanEx   = (int*)(ws + 339968);          //    200,704
    int*   blockSum = (int*)(ws + 540672);          //      1,024
    int*   blockBase= (int*)(ws + 541696);          //      1,024
    int*   cur      = (int*)(ws + 542720);          //    200,704
    int2*  edgeS    = (int2*)(ws + 743424);         //  6,400,000
    short* Sg       = (short*)(ws + 7143424);       // 12,800,000
    short* Dg       = (short*)(ws + 19943424);      // 12,800,000  -> total 32,743,424

    hipMemsetAsync(out, 0, (size_t)NN * HID * sizeof(float), stream);
    hipMemsetAsync(counts, 0, 200704, stream);

    fused_prep<<<3397, 256, 0, stream>>>(ei + NE, counts, W1, W2, Wo,
                                         W1aT, W1bT, W1cT, W2t, Wot);
    k_scan1<<<SCAN_B, 256, 0, stream>>>(counts, scanEx, blockSum);
    k_scan2<<<1, 256, 0, stream>>>(blockSum, blockBase);
    k_scan3<<<SCAN_B, 256, 0, stream>>>(scanEx, blockBase, cur);
    k_permute<<<3125, 256, 0, stream>>>(ei, ei + NE, cur, edgeS);
    sd_kernel<<<(NN + 63) / 64, 256, 0, stream>>>(nf, W1aT, W1bT, Sg, Dg);
    edge_kernel<<<NE / 128, 512, 0, stream>>>(Sg, Dg, pos, edgeS,
                                              W1cT, b1, W2t, b2, out);
    out_kernel<<<(NN + 63) / 64, 256, 0, stream>>>(out, counts, Wot, bo);
}